// Round 3
// baseline (372.397 us; speedup 1.0000x reference)
//
#include <hip/hip_runtime.h>

#define BB 16
#define HH 512
#define WW 512
#define HWP (HH*WW)
#define NMAP ((size_t)BB*HWP)

struct __align__(16) V4 { float x, y, z, w; };
__device__ __forceinline__ V4 v4(float a, float b, float c, float d) { V4 r; r.x=a; r.y=b; r.z=c; r.w=d; return r; }
__device__ __forceinline__ V4 v4z() { return v4(0.f,0.f,0.f,0.f); }
__device__ __forceinline__ V4 vadd(V4 a, V4 b) { return v4(a.x+b.x, a.y+b.y, a.z+b.z, a.w+b.w); }
__device__ __forceinline__ V4 vsub(V4 a, V4 b) { return v4(a.x-b.x, a.y-b.y, a.z-b.z, a.w-b.w); }

// ---------------------------------------------------------------------------
// K1: stages 1 (P=1, eps=.16) + 2 (P=3, eps=.04) fused in one vertical
// software pipeline. 256 thr = full row (2 cols/thread). One LDS exchange +
// ONE barrier per phase (double-buffered rows). Phase k (A1-row k):
//   write G1=(cs1, A1(k-1)) G2=(cs2, A2(k-7))  [cs2 centered k-6]
//   barrier; window sums -> A1(k), HA1(k-1), A2(k-6), HA2(k-7)
//   ca1 ring -> (a1,b1)(k-2) -> sq1(k-2); ca2 ring -> (a2,b2)(k-10)
//   emit pq1(k-2), [sq2,pq2](k-10). Rings all static-indexed (full unroll).
// ---------------------------------------------------------------------------
template <int CH>
__global__ __launch_bounds__(256, 2)
void k1(const float* __restrict__ x, float2* __restrict__ sq2o,
        float2* __restrict__ pq1o, float2* __restrict__ pq2o)
{
    constexpr int NIT = CH + 17;
    constexpr int NCH = HH / CH;
    __shared__ V4 G1[2][514];   // idx = col+1 ; pads {0, 513}
    __shared__ V4 G2[2][518];   // idx = col+3 ; pads {0,1,2, 515,516,517}

    const int t  = threadIdx.x;
    const int c0 = 2 * t, c1 = c0 + 1;
    int bid = blockIdx.x;
    bid = (bid & 7) * ((BB * NCH) / 8) + (bid >> 3);     // XCD-chunked swizzle
    const int b  = bid / NCH;
    const int h0 = (bid % NCH) * CH;
    const size_t mb_ = (size_t)b * HWP;
    const float* xb = x + (size_t)b * 3 * HWP;

    if (t < 16) {                       // zero halo slots, both buffers
        int bf = t & 1, s = t >> 1;     // s = 0..7
        if (s < 2) G1[bf][s ? 513 : 0] = v4z();
        else { int p = s - 2; G2[bf][p < 3 ? p : (515 + p - 3)] = v4z(); }
    }

    auto cwf = [&](int c, int P) -> float {
        int lo = c - P < 0 ? 0 : c - P, hi = c + P > WW-1 ? WW-1 : c + P;
        return (float)(hi - lo + 1);
    };
    const float cw10 = cwf(c0,1), cw11 = cwf(c1,1);
    const float cw20 = cwf(c0,3), cw21 = cwf(c1,3);

    V4 xr[5], h1r[3], s1r[9], h2r[7];
#pragma unroll
    for (int i = 0; i < 5; ++i) xr[i] = v4z();
#pragma unroll
    for (int i = 0; i < 3; ++i) h1r[i] = v4z();
#pragma unroll
    for (int i = 0; i < 9; ++i) s1r[i] = v4z();
#pragma unroll
    for (int i = 0; i < 7; ++i) h2r[i] = v4z();
    V4 cs1 = v4z(), cs2 = v4z(), ca1 = v4z(), ca2 = v4z(), pv1 = v4z(), pv2 = v4z();

    auto ldx = [&](int r) -> V4 {       // (s,q) at row r for cols c0,c1 (0 outside)
        if ((unsigned)r >= (unsigned)HH) return v4z();
        size_t o = (size_t)r * WW + c0;
        float2 a0 = *(const float2*)(xb + o);
        float2 a1 = *(const float2*)(xb + o + HWP);
        float2 a2 = *(const float2*)(xb + o + 2*HWP);
        return v4(a0.x+a1.x+a2.x, a0.x*a0.x + a1.x*a1.x + a2.x*a2.x,
                  a0.y+a1.y+a2.y, a0.y*a0.y + a1.y*a1.y + a2.y*a2.y);
    };

    // prime xr: rows h0-8..h0-6 -> slots 1..3 (slot(row) = (row-(h0-9)) % 5)
#pragma unroll
    for (int j = 0; j < 3; ++j) {
        int r = h0 - 8 + j;
        if (r >= 0) xr[1 + j] = ldx(r);
    }
    cs1 = vadd(vadd(xr[1], xr[2]), xr[3]);
    __syncthreads();

#pragma unroll
    for (int kk = 0; kk < NIT; ++kk) {
        const int k  = h0 - 7 + kk;
        const int bf = kk & 1;
        G1[bf][c0+1] = v4(cs1.x, cs1.y, pv1.x, pv1.y);
        G1[bf][c0+2] = v4(cs1.z, cs1.w, pv1.z, pv1.w);
        G2[bf][c0+3] = v4(cs2.x, cs2.y, pv2.x, pv2.y);
        G2[bf][c0+4] = v4(cs2.z, cs2.w, pv2.z, pv2.w);
        V4 nx = v4z();
        if (kk < NIT - 1) nx = ldx(k + 2);          // prefetch before barrier
        __syncthreads();

        V4 ga = G1[bf][c0], gb = G1[bf][c0+1], gc = G1[bf][c0+2], gd = G1[bf][c0+3];
        V4 W10 = vadd(vadd(ga, gb), gc);
        V4 W11 = vadd(vadd(gb, gc), gd);
        V4 g0 = G2[bf][c0],   g1 = G2[bf][c0+1], g2 = G2[bf][c0+2], g3 = G2[bf][c0+3];
        V4 g4 = G2[bf][c0+4], g5 = G2[bf][c0+5], g6 = G2[bf][c0+6], g7 = G2[bf][c0+7];
        V4 W20 = vadd(vadd(vadd(g0, g1), vadd(g2, g3)), vadd(vadd(g4, g5), g6));
        V4 W21 = vadd(vsub(W20, g0), g7);

        // A1(k)
        V4 A1n = v4z();
        if ((unsigned)k < (unsigned)HH) {
            int lo = k-1 < 0 ? 0 : k-1, hi = k+1 > HH-1 ? HH-1 : k+1;
            float chh = (float)(hi - lo + 1);
            float rn0 = 1.f/(3.f*chh*cw10), rn1 = 1.f/(3.f*chh*cw11);
            float m0 = W10.x*rn0, m1 = W11.x*rn1;
            float v0 = W10.y*rn0 - m0*m0, v1 = W11.y*rn1 - m1*m1;
            float a0 = v0/(v0 + 0.16f), a1 = v1/(v1 + 0.16f);
            A1n = v4(a0, m0*(1.f-a0), a1, m1*(1.f-a1));
        }
        V4 HA1 = v4(W10.z, W10.w, W11.z, W11.w);
        ca1 = vadd(ca1, vsub(HA1, h1r[kk % 3])); h1r[kk % 3] = HA1;

        // sq1 / (a1,b1) at row k-2
        V4 xv = xr[kk % 5];
        float mA0 = 3.f*ca1.x, mb0 = 3.f*ca1.y, mA1c = 3.f*ca1.z, mb1c = 3.f*ca1.w;
        V4 s1n = v4z();
        if ((unsigned)(k-2) < (unsigned)HH) {
            s1n = v4(mA0*xv.x + 3.f*mb0,
                     mA0*mA0*xv.y + 2.f*mA0*mb0*xv.x + 3.f*mb0*mb0,
                     mA1c*xv.z + 3.f*mb1c,
                     mA1c*mA1c*xv.w + 2.f*mA1c*mb1c*xv.z + 3.f*mb1c*mb1c);
        }
        if (kk >= 9 && kk <= CH + 8) {              // emit (a1,b1) at row k-2
            size_t o = mb_ + (size_t)(k-2) * WW + c0;
            *((float4*)&pq1o[o]) = make_float4(mA0, mb0, mA1c, mb1c);
        }

        // A2(k-6)
        V4 A2n = v4z();
        {
            int r2 = k - 6;
            if ((unsigned)r2 < (unsigned)HH) {
                int lo = r2-3 < 0 ? 0 : r2-3, hi = r2+3 > HH-1 ? HH-1 : r2+3;
                float chh = (float)(hi - lo + 1);
                float rn0 = 1.f/(3.f*chh*cw20), rn1 = 1.f/(3.f*chh*cw21);
                float m0 = W20.x*rn0, m1 = W21.x*rn1;
                float v0 = W20.y*rn0 - m0*m0, v1 = W21.y*rn1 - m1*m1;
                float a0 = v0/(v0 + 0.04f), a1 = v1/(v1 + 0.04f);
                A2n = v4(a0, m0*(1.f-a0), a1, m1*(1.f-a1));
            }
        }
        V4 HA2 = v4(W20.z, W20.w, W21.z, W21.w);
        ca2 = vadd(ca2, vsub(HA2, h2r[kk % 7])); h2r[kk % 7] = HA2;

        if (kk >= 17 && kk <= CH + 16) {            // emit sq2 + (a2,b2) at row k-10
            V4 s1v = s1r[(kk + 1) % 9];
            float a2  = 3.f*ca2.x, b2  = 3.f*ca2.y;
            float a2c = 3.f*ca2.z, b2c = 3.f*ca2.w;
            size_t o = mb_ + (size_t)(k-10) * WW + c0;
            *((float4*)&sq2o[o]) = make_float4(
                a2*s1v.x + 3.f*b2,
                a2*a2*s1v.y + 2.f*a2*b2*s1v.x + 3.f*b2*b2,
                a2c*s1v.z + 3.f*b2c,
                a2c*a2c*s1v.w + 2.f*a2c*b2c*s1v.z + 3.f*b2c*b2c);
            *((float4*)&pq2o[o]) = make_float4(a2, b2, a2c, b2c);
        }

        if (kk < NIT - 1) {
            cs2 = vadd(cs2, vsub(s1n, s1r[(kk + 2) % 9]));
            s1r[kk % 9] = s1n;
            cs1 = vadd(cs1, vsub(nx, xr[(kk + 1) % 5]));
            xr[(kk + 4) % 5] = nx;
            pv1 = A1n; pv2 = A2n;
        }
    }
}

// ---------------------------------------------------------------------------
// K2: stage 3 (P=7, eps=.01) + folded epilogue (diffs + 1x1 conv).
// Same single-barrier pipeline. Phase k: A3(k); emit out rows at h = k-8.
// ---------------------------------------------------------------------------
template <int CH>
__global__ __launch_bounds__(256, 2)
void k2(const float2* __restrict__ sq2, const float2* __restrict__ pq1,
        const float2* __restrict__ pq2, const float* __restrict__ x,
        const float* __restrict__ wt, float* __restrict__ outp)
{
    constexpr int NIT = CH + 15;
    constexpr int NCH = HH / CH;
    __shared__ V4 G3[2][526];   // idx = col+7 ; pads {0..6, 519..525}

    const int t  = threadIdx.x;
    const int c0 = 2 * t, c1 = c0 + 1;
    int bid = blockIdx.x;
    bid = (bid & 7) * ((BB * NCH) / 8) + (bid >> 3);
    const int b  = bid / NCH;
    const int h0 = (bid % NCH) * CH;
    const size_t mb_ = (size_t)b * HWP;
    const float2* sb = sq2 + mb_;
    const float*  xb = x + (size_t)b * 3 * HWP;
    float* ob = outp + (size_t)b * 3 * HWP;

    if (t < 28) {
        int bf = t & 1, s = t >> 1;     // s = 0..13
        G3[bf][s < 7 ? s : (519 + s - 7)] = v4z();
    }
    auto cwf = [&](int c) -> float {
        int lo = c - 7 < 0 ? 0 : c - 7, hi = c + 7 > WW-1 ? WW-1 : c + 7;
        return (float)(hi - lo + 1);
    };
    const float cw30 = cwf(c0), cw31 = cwf(c1);

    float wr[27];
#pragma unroll
    for (int i = 0; i < 27; ++i) wr[i] = wt[i];

    V4 h3r[15];
#pragma unroll
    for (int i = 0; i < 15; ++i) h3r[i] = v4z();
    V4 cs3 = v4z(), ca3 = v4z(), pv3 = v4z();

    auto lds2 = [&](int r) -> V4 {
        if ((unsigned)r >= (unsigned)HH) return v4z();
        float4 v = *((const float4*)&sb[(size_t)r * WW + c0]);
        return v4(v.x, v.y, v.z, v.w);
    };

#pragma unroll
    for (int j = 0; j < 15; ++j) cs3 = vadd(cs3, lds2(h0 - 14 + j));
    __syncthreads();

#pragma unroll
    for (int kk = 0; kk < NIT; ++kk) {
        const int k  = h0 - 7 + kk;
        const int bf = kk & 1;
        G3[bf][c0+7] = v4(cs3.x, cs3.y, pv3.x, pv3.y);
        G3[bf][c0+8] = v4(cs3.z, cs3.w, pv3.z, pv3.w);
        V4 nin = v4z(), nout = v4z();
        if (kk < NIT - 1) { nin = lds2(k + 8); nout = lds2(k - 7); }
        float4 q1v = make_float4(0,0,0,0), q2v = make_float4(0,0,0,0);
        float2 xe0 = make_float2(0,0), xe1 = xe0, xe2 = xe0;
        if (kk >= 15) {                              // prefetch emit-row inputs
            size_t o = mb_ + (size_t)(k-8) * WW + c0;
            q1v = *((const float4*)&pq1[o]);
            q2v = *((const float4*)&pq2[o]);
            size_t xo = (size_t)(k-8) * WW + c0;
            xe0 = *(const float2*)(xb + xo);
            xe1 = *(const float2*)(xb + xo + HWP);
            xe2 = *(const float2*)(xb + xo + 2*HWP);
        }
        __syncthreads();

        V4 g[16];
#pragma unroll
        for (int j = 0; j < 16; ++j) g[j] = G3[bf][c0 + j];
        V4 s01 = vadd(g[0], g[1]),   s23 = vadd(g[2], g[3]);
        V4 s45 = vadd(g[4], g[5]),   s67 = vadd(g[6], g[7]);
        V4 s89 = vadd(g[8], g[9]),   sab = vadd(g[10], g[11]);
        V4 scd = vadd(g[12], g[13]);
        V4 W0 = vadd(vadd(vadd(s01, s23), vadd(s45, s67)),
                     vadd(vadd(s89, sab), vadd(scd, g[14])));
        V4 W1 = vadd(vsub(W0, g[0]), g[15]);

        V4 A3n = v4z();
        if ((unsigned)k < (unsigned)HH) {
            int lo = k-7 < 0 ? 0 : k-7, hi = k+7 > HH-1 ? HH-1 : k+7;
            float chh = (float)(hi - lo + 1);
            float rn0 = 1.f/(3.f*chh*cw30), rn1 = 1.f/(3.f*chh*cw31);
            float m0 = W0.x*rn0, m1 = W1.x*rn1;
            float v0 = W0.y*rn0 - m0*m0, v1 = W1.y*rn1 - m1*m1;
            float a0 = v0/(v0 + 0.01f), a1 = v1/(v1 + 0.01f);
            A3n = v4(a0, m0*(1.f-a0), a1, m1*(1.f-a1));
        }
        V4 HA3 = v4(W0.z, W0.w, W1.z, W1.w);
        ca3 = vadd(ca3, vsub(HA3, h3r[kk % 15])); h3r[kk % 15] = HA3;

        if (kk >= 15) {                              // emit out row h = k-8
            float a3  = 3.f*ca3.x, b3  = 3.f*ca3.y;
            float a3c = 3.f*ca3.z, b3c = 3.f*ca3.w;
            float r0[3], r1[3];
#pragma unroll
            for (int c = 0; c < 2; ++c) {
                float P1 = c ? q1v.z : q1v.x, Q1 = c ? q1v.w : q1v.y;
                float a2 = c ? q2v.z : q2v.x, b2 = c ? q2v.w : q2v.y;
                float a3v = c ? a3c : a3,     b3v = c ? b3c : b3;
                float P2 = a2 * P1,  Q2 = a2 * Q1 + b2;
                float P3 = a3v * P2, Q3 = a3v * Q2 + b3v;
                float al[3] = {1.f - P1, P1 - P2, P2 - P3};
                float be[3] = {-Q1,      Q1 - Q2, Q2 - Q3};
                float x0 = c ? xe0.y : xe0.x;
                float x1 = c ? xe1.y : xe1.x;
                float x2 = c ? xe2.y : xe2.x;
                float* rr = c ? r1 : r0;
#pragma unroll
                for (int oc = 0; oc < 3; ++oc) {
                    float acc = 0.f;
#pragma unroll
                    for (int gg = 0; gg < 3; ++gg) {
                        float wa = wr[oc*9 + gg*3 + 0];
                        float wb = wr[oc*9 + gg*3 + 1];
                        float wc = wr[oc*9 + gg*3 + 2];
                        acc += al[gg] * (wa*x0 + wb*x1 + wc*x2)
                             + be[gg] * (wa + wb + wc);
                    }
                    rr[oc] = acc;
                }
            }
            size_t xo = (size_t)(k-8) * WW + c0;
#pragma unroll
            for (int oc = 0; oc < 3; ++oc)
                *((float2*)(ob + (size_t)oc * HWP + xo)) = make_float2(r0[oc], r1[oc]);
        }

        if (kk < NIT - 1) {
            cs3 = vadd(cs3, vsub(nin, nout));
            pv3 = A3n;
        }
    }
}

extern "C" void kernel_launch(void* const* d_in, const int* in_sizes, int n_in,
                              void* d_out, int out_size, void* d_ws, size_t ws_size,
                              hipStream_t stream) {
    (void)in_sizes; (void)n_in; (void)out_size; (void)ws_size;
    const float* x  = (const float*)d_in[0];
    const float* w1 = (const float*)d_in[1];
    float* out = (float*)d_out;

    float2* sq2 = (float2*)d_ws;          // F2 moments
    float2* pq1 = sq2 + NMAP;             // (a1,b1) = 3*box(A1), 3*box(b1)
    float2* pq2 = pq1 + NMAP;             // (a2,b2)

    constexpr int CH = 16;
    dim3 bl(256), g(BB * (HH / CH));      // 512 blocks each

    k1<CH><<<g, bl, 0, stream>>>(x, sq2, pq1, pq2);
    k2<CH><<<g, bl, 0, stream>>>(sq2, pq1, pq2, x, w1, out);
}

// Round 4
// 203.757 us; speedup vs baseline: 1.8276x; 1.8276x over previous
//
#include <hip/hip_runtime.h>

#define BB 16
#define HH 512
#define WW 512
#define HWP (HH*WW)
#define NMAP ((size_t)BB*HWP)

struct __align__(16) V4 { float x, y, z, w; };
__device__ __forceinline__ V4 v4(float a, float b, float c, float d) { V4 r; r.x=a; r.y=b; r.z=c; r.w=d; return r; }
__device__ __forceinline__ V4 v4z() { return v4(0.f,0.f,0.f,0.f); }
__device__ __forceinline__ V4 vadd(V4 a, V4 b) { return v4(a.x+b.x, a.y+b.y, a.z+b.z, a.w+b.w); }
__device__ __forceinline__ V4 vsub(V4 a, V4 b) { return v4(a.x-b.x, a.y-b.y, a.z-b.z, a.w-b.w); }

// ---------------------------------------------------------------------------
// Guided-filter stage (round-2 semantics, leaner phases).
// 256 thr = full 512-wide row, 2 cols/thread. Per phase (A-row r = h0-P+j):
//   write exchange: PS[t] = e(c0)+e(c1), EV[t] = e(c0), OD[t] = e(c1),
//     where e = (cs.s, cs.q, ca.A, ca.b); double-buffered -> ONE barrier.
//   prefetch next in-row (1 phase deep) + retire-row + emit-row inputs.
//   barrier; window W = sum of 2PH+1 pair-sums + 2 edge singles
//     (P=7: 9 reads vs 16; exact same math reassociated).
//   emit row h = r-P-1; compute A(r); ca += A(r) - ring[j%RD] (static idx).
// MODE 1: in = x (s,q inline)  MODE 2: in = (s,q) map  MODE 3: + epilogue.
// ---------------------------------------------------------------------------
template <int P, int CH, int MODE>
__global__ __launch_bounds__(256, 2)
void stage(const float* __restrict__ xin, const float2* __restrict__ sqin,
           float2* __restrict__ abo, float2* __restrict__ sqo,
           const float2* __restrict__ abp1, const float2* __restrict__ abp2,
           const float* __restrict__ wt, float* __restrict__ outp, float eps)
{
    constexpr int PH  = (P - 1) / 2;
    constexpr int RD  = 2*P + 1;
    constexpr int NIT = CH + 2*P + 1;
    constexpr int NCH = HH / CH;
    constexpr int NWG = BB * NCH;
    constexpr int NPS = 256 + 2*PH;      // pair-sums, shift PH
    constexpr int NEV = 257 + PH;        // even cols, shift 0, right halo
    constexpr int NOD = 258 + PH;        // odd cols, shift PH+1, left halo

    __shared__ V4 PS[2][NPS];
    __shared__ V4 EV[2][NEV];
    __shared__ V4 OD[2][NOD];

    const int t  = threadIdx.x;
    int bx = blockIdx.x;
    int bid = (bx & 7) * (NWG / 8) + (bx >> 3);      // XCD-chunked swizzle
    const int b  = bid / NCH;
    const int h0 = (bid % NCH) * CH;
    const size_t mb_ = (size_t)b * HWP;
    const float*  xb  = (MODE != 2) ? (xin + (size_t)b * 3 * HWP) : nullptr;
    const float2* sqb = (MODE != 1) ? (sqin + mb_) : nullptr;

    // one-time halo zeroing (phases never overwrite these slots)
    if (t < PH) {
        PS[0][t] = v4z(); PS[1][t] = v4z();
        PS[0][256+PH+t] = v4z(); PS[1][256+PH+t] = v4z();
    }
    if (t < PH + 1) {
        OD[0][t] = v4z(); OD[1][t] = v4z();
        EV[0][256+t] = v4z(); EV[1][256+t] = v4z();
    }

    const int c0 = 2*t, c1 = c0 + 1;
    auto cwf = [&](int c) -> float {
        int lo = c - P < 0 ? 0 : c - P, hi = c + P > WW-1 ? WW-1 : c + P;
        return (float)(hi - lo + 1);
    };
    const float cw0 = cwf(c0), cw1 = cwf(c1);

    auto loadrow = [&](int rr) -> V4 {   // (s0,q0,s1,q1) at row rr
        if constexpr (MODE == 1) {
            size_t o = (size_t)rr * WW + c0;
            float2 a0 = *(const float2*)(xb + o);
            float2 a1 = *(const float2*)(xb + o + HWP);
            float2 a2 = *(const float2*)(xb + o + 2*HWP);
            return v4(a0.x+a1.x+a2.x, a0.x*a0.x + a1.x*a1.x + a2.x*a2.x,
                      a0.y+a1.y+a2.y, a0.y*a0.y + a1.y*a1.y + a2.y*a2.y);
        } else {
            float4 v = ((const float4*)(sqb + (size_t)rr * WW))[t];
            return v4(v.x, v.y, v.z, v.w);
        }
    };

    V4 csv = v4z(), cav = v4z();
    V4 rgv[RD];
#pragma unroll
    for (int i = 0; i < RD; ++i) rgv[i] = v4z();

    // prime cs: rows h0-2P .. h0 (centered h0-P)
#pragma unroll
    for (int d = 0; d <= 2*P; ++d) {
        int rr = h0 - 2*P + d;
        if (rr >= 0) csv = vadd(csv, loadrow(rr));   // uniform
    }
    V4 nin = loadrow(h0 + 1);            // in-row for advance at end of j=0

    float w1r[27];
    if constexpr (MODE == 3) {
#pragma unroll
        for (int k = 0; k < 27; ++k) w1r[k] = wt[k];
    }
    __syncthreads();                     // cover halo zeroing

#pragma unroll
    for (int j = 0; j < NIT; ++j) {
        const int r  = h0 - P + j;
        const int bf = j & 1;
        V4 e0 = v4(csv.x, csv.y, cav.x, cav.y);
        V4 e1 = v4(csv.z, csv.w, cav.z, cav.w);
        PS[bf][PH + t]     = vadd(e0, e1);
        EV[bf][t]          = e0;
        OD[bf][PH + 1 + t] = e1;

        // global prefetches (consumed after the barrier)
        V4 nin2 = v4z(), outv = v4z();
        if (j < NIT - 2) { int rr = r + 2 + P; if (rr < HH) nin2 = loadrow(rr); }
        if (j < NIT - 1) { int rr = r - P;     if (rr >= 0) outv = loadrow(rr); }
        const int h = r - P - 1;                       // emit row this phase
        V4 dv = v4z();
        float4 q1v = make_float4(0,0,0,0), q2v = make_float4(0,0,0,0);
        float2 xe0 = make_float2(0,0), xe1 = xe0, xe2 = xe0;
        if (j >= 2*P + 1) {
            if constexpr (MODE != 3) {
                dv = loadrow(h);                       // cache-hot re-read
            } else {
                size_t o = mb_ + (size_t)h * WW + c0;
                q1v = *((const float4*)&abp1[o]);
                q2v = *((const float4*)&abp2[o]);
                size_t xo = (size_t)h * WW + c0;
                xe0 = *(const float2*)(xb + xo);
                xe1 = *(const float2*)(xb + xo + HWP);
                xe2 = *(const float2*)(xb + xo + 2*HWP);
            }
        }
        __syncthreads();

        V4 S = v4z();
#pragma unroll
        for (int i = -PH; i <= PH; ++i) S = vadd(S, PS[bf][PH + t + i]);
        V4 W0 = vadd(S, OD[bf][t]);            // + col c0-P  (odd single)
        V4 W1 = vadd(S, EV[bf][t + PH + 1]);   // + col c1+P  (even single)

        if (j >= 2*P + 1) {
            if constexpr (MODE != 3) {
                size_t o = mb_ + (size_t)h * WW + c0;
                *((float4*)&abo[o]) = make_float4(W0.z, W0.w, W1.z, W1.w);
                float mA0 = 3.f*W0.z, mb0 = 3.f*W0.w;
                float mA1 = 3.f*W1.z, mb1 = 3.f*W1.w;
                *((float4*)&sqo[o]) = make_float4(
                    mA0*dv.x + 3.f*mb0,
                    mA0*mA0*dv.y + 2.f*mA0*mb0*dv.x + 3.f*mb0*mb0,
                    mA1*dv.z + 3.f*mb1,
                    mA1*mA1*dv.w + 2.f*mA1*mb1*dv.z + 3.f*mb1*mb1);
            } else {
                float a3  = 3.f*W0.z, b3  = 3.f*W0.w;
                float a3c = 3.f*W1.z, b3c = 3.f*W1.w;
                float r0[3], r1[3];
#pragma unroll
                for (int c = 0; c < 2; ++c) {
                    float P1 = 3.f * (c ? q1v.z : q1v.x), Q1 = 3.f * (c ? q1v.w : q1v.y);
                    float a2 = 3.f * (c ? q2v.z : q2v.x), b2 = 3.f * (c ? q2v.w : q2v.y);
                    float a3v = c ? a3c : a3,             b3v = c ? b3c : b3;
                    float P2 = a2 * P1,  Q2 = a2 * Q1 + b2;
                    float P3 = a3v * P2, Q3 = a3v * Q2 + b3v;
                    float al[3] = {1.f - P1, P1 - P2, P2 - P3};
                    float be[3] = {-Q1,      Q1 - Q2, Q2 - Q3};
                    float x0 = c ? xe0.y : xe0.x;
                    float x1 = c ? xe1.y : xe1.x;
                    float x2 = c ? xe2.y : xe2.x;
                    float* rr_ = c ? r1 : r0;
#pragma unroll
                    for (int oc = 0; oc < 3; ++oc) {
                        float acc = 0.f;
#pragma unroll
                        for (int gg = 0; gg < 3; ++gg) {
                            float wa = w1r[oc*9 + gg*3 + 0];
                            float wb = w1r[oc*9 + gg*3 + 1];
                            float wc = w1r[oc*9 + gg*3 + 2];
                            acc += al[gg] * (wa*x0 + wb*x1 + wc*x2)
                                 + be[gg] * (wa + wb + wc);
                        }
                        rr_[oc] = acc;
                    }
                }
                float* ob = outp + (size_t)b * 3 * HWP + (size_t)h * WW + c0;
#pragma unroll
                for (int oc = 0; oc < 3; ++oc)
                    *((float2*)(ob + (size_t)oc * HWP)) = make_float2(r0[oc], r1[oc]);
            }
        }

        if (j < NIT - 1) {
            // A(r), b(r) from first-box window sums
            V4 Av = v4z();
            if ((unsigned)r < (unsigned)HH) {          // uniform
                int lo = r-P < 0 ? 0 : r-P, hi = r+P > HH-1 ? HH-1 : r+P;
                float chh = (float)(hi - lo + 1);
                float rn0 = 1.f/(3.f*chh*cw0), rn1 = 1.f/(3.f*chh*cw1);
                float m0 = W0.x*rn0, m1 = W1.x*rn1;
                float v0 = W0.y*rn0 - m0*m0, v1 = W1.y*rn1 - m1*m1;
                float a0 = v0/(v0 + eps), a1 = v1/(v1 + eps);
                Av = v4(a0, m0*(1.f-a0), a1, m1*(1.f-a1));
            }
            const int ri = j % RD;                     // static under unroll
            cav = vadd(cav, vsub(Av, rgv[ri]));
            rgv[ri] = Av;
            csv = vadd(csv, vsub(nin, outv));
            nin = nin2;
        }
    }
}

extern "C" void kernel_launch(void* const* d_in, const int* in_sizes, int n_in,
                              void* d_out, int out_size, void* d_ws, size_t ws_size,
                              hipStream_t stream) {
    (void)in_sizes; (void)n_in; (void)out_size; (void)ws_size;
    const float* x  = (const float*)d_in[0];
    const float* w1 = (const float*)d_in[1];
    float* out = (float*)d_out;

    float2* sq1 = (float2*)d_ws;          // F1 moments
    float2* sq2 = sq1 + NMAP;             // F2 moments
    float2* ab1 = sq2 + NMAP;             // raw (boxA, boxB) of stage 1
    float2* ab2 = ab1 + NMAP;             // raw (boxA, boxB) of stage 2

    dim3 bl(256);

    // stage 1: k=3  (P=1), eps=0.16 — s,q inline; CH=4 -> 2048 blocks
    stage<1,4,1><<<dim3(BB*(HH/4)), bl, 0, stream>>>(x, nullptr, ab1, sq1,
                                        nullptr, nullptr, nullptr, nullptr, 0.16f);
    // stage 2: k=7  (P=3), eps=0.04 ; CH=8 -> 1024 blocks
    stage<3,8,2><<<dim3(BB*(HH/8)), bl, 0, stream>>>(nullptr, sq1, ab2, sq2,
                                        nullptr, nullptr, nullptr, nullptr, 0.04f);
    // stage 3: k=15 (P=7), eps=0.01 — epilogue folded; CH=8 -> 1024 blocks
    stage<7,8,3><<<dim3(BB*(HH/8)), bl, 0, stream>>>(x, sq2, nullptr, nullptr,
                                        ab1, ab2, w1, out, 0.01f);
}